// Round 7
// baseline (972.481 us; speedup 1.0000x reference)
//
#include <hip/hip_runtime.h>
#include <hip/hip_fp16.h>

#define HID 64

struct alignas(8)  H4 { __half2 a, b; };
struct alignas(16) H8 { __half2 h[4]; };

typedef _Float16 f16x8 __attribute__((ext_vector_type(8)));
typedef float    f32x4 __attribute__((ext_vector_type(4)));

// ===========================================================================
// CSR build: histogram + scan + permutation (+ fp16 edge-feature reorder)
// ===========================================================================
__global__ __launch_bounds__(256) void deg_count(const int* __restrict__ dst,
                                                 int* __restrict__ deg, int E) {
    int e = blockIdx.x * 256 + threadIdx.x;
    if (e < E) atomicAdd(&deg[dst[e]], 1);
}

__global__ __launch_bounds__(256) void scan1(const int* __restrict__ deg,
                                             int* __restrict__ rowptr,
                                             int* __restrict__ bsums, int N) {
    __shared__ int s[256];
    const int t = threadIdx.x;
    const int base = blockIdx.x * 2048 + t * 8;
    int v[8], tot = 0;
    #pragma unroll
    for (int i = 0; i < 8; i++) {
        int x = (base + i < N) ? deg[base + i] : 0;
        v[i] = tot; tot += x;
    }
    s[t] = tot; __syncthreads();
    for (int off = 1; off < 256; off <<= 1) {
        int a = (t >= off) ? s[t - off] : 0;
        __syncthreads(); s[t] += a; __syncthreads();
    }
    const int texcl = s[t] - tot;
    #pragma unroll
    for (int i = 0; i < 8; i++)
        if (base + i < N) rowptr[base + i] = texcl + v[i];
    if (t == 255) bsums[blockIdx.x] = s[255];
}

__global__ void scan2(int* bsums, int NB) {
    if (blockIdx.x == 0 && threadIdx.x == 0) {
        int run = 0;
        for (int i = 0; i < NB; i++) { int x = bsums[i]; bsums[i] = run; run += x; }
    }
}

__global__ __launch_bounds__(256) void scan3(int* __restrict__ rowptr,
                                             const int* __restrict__ bsums,
                                             int N, int E) {
    int idx = blockIdx.x * 256 + threadIdx.x;
    if (idx < N) rowptr[idx] += bsums[idx >> 11];
    if (idx == 0) rowptr[N] = E;
}

__global__ __launch_bounds__(256) void permute_k(
    const int* __restrict__ src, const int* __restrict__ dst,
    const int* __restrict__ rowptr, int* __restrict__ cursor,
    const float* __restrict__ Xe, __half* __restrict__ Xes,
    unsigned* __restrict__ pks, int E)
{
    int e = blockIdx.x * 256 + threadIdx.x;
    if (e >= E) return;
    int d = dst[e];
    int pos = rowptr[d] + atomicAdd(&cursor[d], 1);
    pks[pos] = ((unsigned)src[e] << 5) | (unsigned)(d & 31);
    const float4* xi = (const float4*)&Xe[(size_t)e * 16];
    float4 x0 = xi[0], x1 = xi[1], x2 = xi[2], x3 = xi[3];
    H8 h0, h1;
    h0.h[0] = __float22half2_rn(make_float2(x0.x, x0.y));
    h0.h[1] = __float22half2_rn(make_float2(x0.z, x0.w));
    h0.h[2] = __float22half2_rn(make_float2(x1.x, x1.y));
    h0.h[3] = __float22half2_rn(make_float2(x1.z, x1.w));
    h1.h[0] = __float22half2_rn(make_float2(x2.x, x2.y));
    h1.h[1] = __float22half2_rn(make_float2(x2.z, x2.w));
    h1.h[2] = __float22half2_rn(make_float2(x3.x, x3.y));
    h1.h[3] = __float22half2_rn(make_float2(x3.z, x3.w));
    H8* xo = (H8*)&Xes[(size_t)pos * 16];
    xo[0] = h0; xo[1] = h1;
}

// ===========================================================================
// pm_dual: PMh[n] = fp16(h@Wm_top + bm), Th[n] = fp16(h@Wu_top + bu)
// ===========================================================================
template<int K1>
__global__ __launch_bounds__(256) void pm_dual(
    const float* __restrict__ Hn,
    const float* __restrict__ Wm, const float* __restrict__ bm,
    const float* __restrict__ Wu, const float* __restrict__ bu,
    __half* __restrict__ PMh, __half* __restrict__ Th, int N)
{
    constexpr int KP = K1 + 4;
    constexpr int P4 = K1 / 4;
    __shared__ float Ws[K1 * 128];
    __shared__ float Xs[32 * KP];

    const int tid = threadIdx.x;
    for (int i = tid; i < K1 * 32; i += 256) {
        const int row = i >> 5, c4 = i & 31;
        float4 v = (c4 < 16) ? *(const float4*)&Wm[row * 64 + c4 * 4]
                             : *(const float4*)&Wu[row * 64 + (c4 - 16) * 4];
        *(float4*)&Ws[row * 128 + c4 * 4] = v;
    }
    const int nbase = blockIdx.x * 32;
    for (int i = tid; i < 32 * P4; i += 256) {
        const int nl = i / P4, part = i % P4;
        const int n = nbase + nl;
        if (n < N)
            *(float4*)&Xs[nl * KP + part * 4] =
                *(const float4*)&Hn[(size_t)n * K1 + part * 4];
    }
    __syncthreads();

    const int c0 = (tid & 31) * 4;
    const int n0 = (tid >> 5) * 4;
    const float4 bv = (c0 < 64) ? *(const float4*)&bm[c0]
                                : *(const float4*)&bu[c0 - 64];

    float4 acc[4];
    #pragma unroll
    for (int i = 0; i < 4; i++) acc[i] = bv;

    #pragma unroll 4
    for (int k = 0; k < K1; k += 4) {
        const float4 w0 = *(const float4*)&Ws[(k + 0) * 128 + c0];
        const float4 w1 = *(const float4*)&Ws[(k + 1) * 128 + c0];
        const float4 w2 = *(const float4*)&Ws[(k + 2) * 128 + c0];
        const float4 w3 = *(const float4*)&Ws[(k + 3) * 128 + c0];
        #pragma unroll
        for (int ni = 0; ni < 4; ni++) {
            const float4 xv = *(const float4*)&Xs[(n0 + ni) * KP + k];
            acc[ni].x += xv.x * w0.x + xv.y * w1.x + xv.z * w2.x + xv.w * w3.x;
            acc[ni].y += xv.x * w0.y + xv.y * w1.y + xv.z * w2.y + xv.w * w3.y;
            acc[ni].z += xv.x * w0.z + xv.y * w1.z + xv.z * w2.z + xv.w * w3.z;
            acc[ni].w += xv.x * w0.w + xv.y * w1.w + xv.z * w2.w + xv.w * w3.w;
        }
    }

    #pragma unroll
    for (int ni = 0; ni < 4; ni++) {
        const int n = nbase + n0 + ni;
        if (n < N) {
            H4 o;
            o.a = __float22half2_rn(make_float2(acc[ni].x, acc[ni].y));
            o.b = __float22half2_rn(make_float2(acc[ni].z, acc[ni].w));
            if (c0 < 64) *(H4*)&PMh[(size_t)n * 64 + c0]      = o;
            else         *(H4*)&Th [(size_t)n * 64 + c0 - 64] = o;
        }
    }
}

// ===========================================================================
// edge_fused (MFMA): per 16-edge chunk per wave:
//   A[e] = [ Xe[e][0:16] | PM[src[e]][16s:16s+16] ]   (K=32)
//   B_s  = [ Mwb[:, 16s:16s+16] ; I16 ]
//   C_s  = Xe@Mwb_s + PM_s   (PM rides the identity, exact)
// relu + run-merged LDS-atomic scatter by dst; fused node-update tail.
// Layouts (m89-verified): A: m=lane&15,k=quad*8+j; B: k=quad*8+j,n=lane&15;
//                         C: col=lane&15, row=quad*4+reg.
// ===========================================================================
__global__ __launch_bounds__(256) void edge_fused(
    const __half*   __restrict__ PMh,   // [N, 64]
    const __half*   __restrict__ Th,    // [N, 64]
    const __half*   __restrict__ Xes,   // [E, 16] dst-sorted
    const unsigned* __restrict__ pks,   // [E] (src<<5)|ld
    const int*      __restrict__ rowptr,
    const float*    __restrict__ Mwb,   // [16, 64]
    const float*    __restrict__ Uwb,   // [64, 64]
    float*          __restrict__ Yout,  // [N, 64]
    int N)
{
    constexpr int AGP = HID + 4;
    __shared__ float aggs[32 * AGP];    // 8.7 KB

    const int tid  = threadIdx.x;
    const int wv   = tid >> 6;
    const int lane = tid & 63;
    const int n    = lane & 15;
    const int quad = lane >> 4;

    // ---- B fragments: [Mwb slice ; identity], built once ----
    f16x8 bfrag[4];
    #pragma unroll
    for (int s = 0; s < 4; s++) {
        f16x8 b;
        #pragma unroll
        for (int jj = 0; jj < 8; jj++) {
            const int k = quad * 8 + jj;
            float w = (k < 16) ? Mwb[k * 64 + 16 * s + n]
                               : ((k - 16) == n ? 1.f : 0.f);
            b[jj] = (_Float16)w;
        }
        bfrag[s] = b;
    }

    for (int i = tid; i < 32 * AGP; i += 256) aggs[i] = 0.f;

    const int nbase  = blockIdx.x * 32;
    const int nend   = (nbase + 32 < N) ? nbase + 32 : N;
    const int estart = rowptr[nbase];
    const int eend   = rowptr[nend];
    __syncthreads();

    int pc = estart + wv * 16;
    unsigned spk_c = 0, spk_n = 0, spk_n2 = 0;
    f16x8 af_c[4], af_n[4];

    // A-frag loader: quads 0-1 read Xe halves, quads 2-3 read PM halves
    auto loadA = [&](int p0, unsigned spk, f16x8* af) {
        const __half* xbase = Xes + (size_t)(p0 + n) * 16 + quad * 8;
        const __half* pbase = PMh + (size_t)(spk >> 5) * 64 + (quad - 2) * 8;
        #pragma unroll
        for (int s = 0; s < 4; s++) {
            const __half* p = (quad < 2) ? xbase : (pbase + 16 * s);
            af[s] = *(const f16x8*)p;
        }
    };

    if (pc < eend) {
        {
            const int pe = pc + n;
            spk_c = pks[pe < eend ? pe : eend - 1];
        }
        if (pc + 64 < eend) {
            const int pe = pc + 64 + n;
            spk_n = pks[pe < eend ? pe : eend - 1];
        }
        loadA(pc, spk_c, af_c);
    }

    for (; pc < eend; pc += 64) {
        const int pn  = pc + 64;
        const int pn2 = pc + 128;

        if (pn < eend) loadA(pn, spk_n, af_n);
        if (pn2 < eend) {
            const int pe = pn2 + n;
            spk_n2 = pks[pe < eend ? pe : eend - 1];
        }

        // dst of this quad's 4 edges (rows of C): from lanes 0..15's spk_c
        int qld[4];
        #pragma unroll
        for (int r = 0; r < 4; r++)
            qld[r] = (int)(__shfl(spk_c, quad * 4 + r) & 31u);

        // 4 MFMAs: C_s[edge=quad*4+r][ch=16s+n]
        f32x4 acc[4];
        #pragma unroll
        for (int s = 0; s < 4; s++)
            acc[s] = __builtin_amdgcn_mfma_f32_16x16x32_f16(
                af_c[s], bfrag[s], (f32x4){0.f, 0.f, 0.f, 0.f}, 0, 0, 0);

        // relu + run-merged scatter
        int ldp = -1;
        float rs0 = 0.f, rs1 = 0.f, rs2 = 0.f, rs3 = 0.f;
        #pragma unroll
        for (int r = 0; r < 4; r++) {
            const bool valid = (pc + quad * 4 + r) < eend;
            const int ld = valid ? qld[r] : -1;
            const float v0 = fmaxf(acc[0][r], 0.f);
            const float v1 = fmaxf(acc[1][r], 0.f);
            const float v2 = fmaxf(acc[2][r], 0.f);
            const float v3 = fmaxf(acc[3][r], 0.f);
            if (ld == ldp) {
                rs0 += v0; rs1 += v1; rs2 += v2; rs3 += v3;
            } else {
                if (ldp >= 0) {
                    float* a = &aggs[ldp * AGP + n];
                    atomicAdd(a +  0, rs0); atomicAdd(a + 16, rs1);
                    atomicAdd(a + 32, rs2); atomicAdd(a + 48, rs3);
                }
                rs0 = v0; rs1 = v1; rs2 = v2; rs3 = v3; ldp = ld;
            }
        }
        if (ldp >= 0) {
            float* a = &aggs[ldp * AGP + n];
            atomicAdd(a +  0, rs0); atomicAdd(a + 16, rs1);
            atomicAdd(a + 32, rs2); atomicAdd(a + 48, rs3);
        }

        spk_c = spk_n; spk_n = spk_n2;
        #pragma unroll
        for (int s = 0; s < 4; s++) af_c[s] = af_n[s];
    }

    __syncthreads();

    // ---- fused node update: y = relu(T + aggs @ Uw_bot), Uwb via L1 ----
    {
        const int c0t = (tid & 15) * 4;
        const int r0  = tid >> 4;
        const int r1  = r0 + 16;
        const int n0g = nbase + r0, n1g = nbase + r1;
        float4 acc0 = make_float4(0.f, 0.f, 0.f, 0.f);
        float4 acc1 = make_float4(0.f, 0.f, 0.f, 0.f);
        if (n0g < N) {
            H4 th = *(const H4*)&Th[(size_t)n0g * 64 + c0t];
            float2 lo = __half22float2(th.a), hi = __half22float2(th.b);
            acc0 = make_float4(lo.x, lo.y, hi.x, hi.y);
        }
        if (n1g < N) {
            H4 th = *(const H4*)&Th[(size_t)n1g * 64 + c0t];
            float2 lo = __half22float2(th.a), hi = __half22float2(th.b);
            acc1 = make_float4(lo.x, lo.y, hi.x, hi.y);
        }
        #pragma unroll 4
        for (int k = 0; k < 64; k += 4) {
            const float4 w0 = *(const float4*)&Uwb[(k + 0) * 64 + c0t];
            const float4 w1 = *(const float4*)&Uwb[(k + 1) * 64 + c0t];
            const float4 w2 = *(const float4*)&Uwb[(k + 2) * 64 + c0t];
            const float4 w3 = *(const float4*)&Uwb[(k + 3) * 64 + c0t];
            const float4 x0 = *(const float4*)&aggs[r0 * AGP + k];
            const float4 x1 = *(const float4*)&aggs[r1 * AGP + k];
            acc0.x += x0.x * w0.x + x0.y * w1.x + x0.z * w2.x + x0.w * w3.x;
            acc0.y += x0.x * w0.y + x0.y * w1.y + x0.z * w2.y + x0.w * w3.y;
            acc0.z += x0.x * w0.z + x0.y * w1.z + x0.z * w2.z + x0.w * w3.z;
            acc0.w += x0.x * w0.w + x0.y * w1.w + x0.z * w2.w + x0.w * w3.w;
            acc1.x += x1.x * w0.x + x1.y * w1.x + x1.z * w2.x + x1.w * w3.x;
            acc1.y += x1.x * w0.y + x1.y * w1.y + x1.z * w2.y + x1.w * w3.y;
            acc1.z += x1.x * w0.z + x1.y * w1.z + x1.z * w2.z + x1.w * w3.z;
            acc1.w += x1.x * w0.w + x1.y * w1.w + x1.z * w2.w + x1.w * w3.w;
        }
        if (n0g < N) {
            float4 o;
            o.x = fmaxf(acc0.x, 0.f); o.y = fmaxf(acc0.y, 0.f);
            o.z = fmaxf(acc0.z, 0.f); o.w = fmaxf(acc0.w, 0.f);
            *(float4*)&Yout[(size_t)n0g * HID + c0t] = o;
        }
        if (n1g < N) {
            float4 o;
            o.x = fmaxf(acc1.x, 0.f); o.y = fmaxf(acc1.y, 0.f);
            o.z = fmaxf(acc1.z, 0.f); o.w = fmaxf(acc1.w, 0.f);
            *(float4*)&Yout[(size_t)n1g * HID + c0t] = o;
        }
    }
}

// ===========================================================================
// pool_head: out[g] = (sum_{n in graph g} y[n]) . Ww + Wb  (sorted batch_idx)
// ===========================================================================
__global__ __launch_bounds__(256) void pool_head(
    const float* __restrict__ Y, const int* __restrict__ bidx,
    const float* __restrict__ Ww, const float* __restrict__ Wb,
    float* __restrict__ out, int N)
{
    const int g = blockIdx.x;
    int a = 0, b = N;
    while (a < b) { int m = (a + b) >> 1; if (bidx[m] < g) a = m + 1; else b = m; }
    const int lo = a;
    b = N;
    while (a < b) { int m = (a + b) >> 1; if (bidx[m] < g + 1) a = m + 1; else b = m; }
    const int hi = a;

    const int tid = threadIdx.x;
    const int c4 = tid & 15, nl = tid >> 4;
    float4 s = make_float4(0.f, 0.f, 0.f, 0.f);
    for (int n = lo + nl; n < hi; n += 16) {
        const float4 v = *(const float4*)&Y[(size_t)n * HID + c4 * 4];
        s.x += v.x; s.y += v.y; s.z += v.z; s.w += v.w;
    }
    __shared__ float red[16 * 68];
    *(float4*)&red[nl * 68 + c4 * 4] = s;
    __syncthreads();
    if (tid < 64) {
        float t = 0.f;
        #pragma unroll
        for (int r = 0; r < 16; r++) t += red[r * 68 + tid];
        t *= Ww[tid];
        #pragma unroll
        for (int off = 32; off; off >>= 1) t += __shfl_down(t, off);
        if (tid == 0) out[g] = t + Wb[0];
    }
}

extern "C" void kernel_launch(void* const* d_in, const int* in_sizes, int n_in,
                              void* d_out, int out_size, void* d_ws, size_t ws_size,
                              hipStream_t stream) {
    const float* H    = (const float*)d_in[0];
    const float* Xe   = (const float*)d_in[1];
    const int*   ids  = (const int*)d_in[2];
    const int*   bidx = (const int*)d_in[3];
    const float* Mw0  = (const float*)d_in[4];
    const float* Mb0  = (const float*)d_in[5];
    const float* Uw0  = (const float*)d_in[6];
    const float* Ub0  = (const float*)d_in[7];
    const float* MwH  = (const float*)d_in[8];   // [3, 80, 64]
    const float* MbH  = (const float*)d_in[9];
    const float* UwH  = (const float*)d_in[10];  // [3, 128, 64]
    const float* UbH  = (const float*)d_in[11];
    const float* Ww   = (const float*)d_in[12];
    const float* Wb   = (const float*)d_in[13];
    float* out = (float*)d_out;

    const int N = in_sizes[0] / 32;
    const int E = in_sizes[1] / 16;
    const int* src = ids;
    const int* dst = ids + E;

    // ---- workspace ----
    float*  hbuf = (float*)d_ws;                       // N*64 f32
    __half* PMh  = (__half*)(hbuf + (size_t)N * HID);  // N*64 h
    __half* Th   = PMh + (size_t)N * HID;              // N*64 h
    __half* Xes  = Th  + (size_t)N * HID;              // E*16 h
    unsigned* pks = (unsigned*)(Xes + (size_t)E * 16); // E u32
    int* rowptr  = (int*)(pks + E);                    // N+1
    int* deg     = rowptr + (N + 1);                   // N
    int* bsums   = deg + N;                            // <=4096

    const int NB = (N + 2047) / 2048;
    const int eblocks = (E + 255) / 256;
    const int ntile   = (N + 31) / 32;

    // ---- CSR build + fp16 edge reorder ----
    hipMemsetAsync(deg, 0, (size_t)N * sizeof(int), stream);
    deg_count<<<eblocks, 256, 0, stream>>>(dst, deg, E);
    scan1<<<NB, 256, 0, stream>>>(deg, rowptr, bsums, N);
    scan2<<<1, 64, 0, stream>>>(bsums, NB);
    scan3<<<(N + 255) / 256, 256, 0, stream>>>(rowptr, bsums, N, E);
    hipMemsetAsync(deg, 0, (size_t)N * sizeof(int), stream);
    permute_k<<<eblocks, 256, 0, stream>>>(src, dst, rowptr, deg,
                                           Xe, Xes, pks, E);

    // ---- layer 0 (K1=32) ----
    pm_dual<32><<<ntile, 256, 0, stream>>>(H, Mw0, Mb0, Uw0, Ub0, PMh, Th, N);
    edge_fused<<<ntile, 256, 0, stream>>>(PMh, Th, Xes, pks, rowptr,
                                          Mw0 + 32 * HID, Uw0 + 32 * HID, hbuf, N);

    // ---- hidden layers (K1=64) ----
    for (int l = 0; l < 3; l++) {
        const float* Mw = MwH + (size_t)l * 80 * HID;
        const float* Uw = UwH + (size_t)l * 128 * HID;
        pm_dual<64><<<ntile, 256, 0, stream>>>(hbuf, Mw, MbH + (size_t)l * HID,
                                               Uw, UbH + (size_t)l * HID, PMh, Th, N);
        edge_fused<<<ntile, 256, 0, stream>>>(PMh, Th, Xes, pks, rowptr,
                                              Mw + 64 * HID, Uw + 64 * HID, hbuf, N);
    }

    // ---- pooling + head ----
    pool_head<<<256, 256, 0, stream>>>(hbuf, bidx, Ww, Wb, out, N);
}